// Round 8
// baseline (681.671 us; speedup 1.0000x reference)
//
#include <hip/hip_runtime.h>
#include <math.h>
#include <float.h>

#define N_ROWS 131072
#define DIM 64
#define KM1 1023
#define THR 1e-4f

// ---- ws layout (bytes) ----
#define DITH_OFF  0         // float[1024][64] plain dithered (repair)
#define D2_OFF    262144    // float[1024] exact-replica d2 (pad 1e30)
#define BP_OFF    266240    // bf16 planes: 16 x [1024 cols][8] = 256 KB
#define CNT_OFF   528384    // u32[1024]
#define FLAGC_OFF 532480    // u32 (+pad)
#define FLAGL_OFF 532544    // u32[131072]
#define IDX_OFF   1056832   // i32[131072]
// end ~1.58 MB

#define OPQ(x) asm volatile("" : "+v"(x))

typedef __attribute__((ext_vector_type(8))) short bf16x8;
typedef __attribute__((ext_vector_type(4))) float f32x4;
typedef __attribute__((address_space(3))) void lds_void;
typedef __attribute__((address_space(1))) const void glob_void;

__device__ __forceinline__ unsigned short f2bf(float x) {
    unsigned u = __float_as_uint(x);
    return (unsigned short)((u + 0x7fffu + ((u >> 16) & 1u)) >> 16);
}
__device__ __forceinline__ float bf2f(unsigned short b) {
    return __uint_as_float(((unsigned)b) << 16);
}

__device__ __forceinline__ float lerp_exact(float lo, float hi, float tt) {
    float hl = __fsub_rn(hi, lo);
    float p  = __fmul_rn(tt, hl);
    OPQ(p);
    float dv = __fadd_rn(lo, p);
    OPQ(dv);
    return dv;
}

// Kernel A: dithered codebook (exact numpy op order) -> plain dith f32,
// exact-replica d2, bf16-split B planes (MFMA layout), zero counts/flagc.
// 16 blocks x 256; thread (kl = t>>2, c = t&3) handles col k dims 16c..16c+15.
__global__ void __launch_bounds__(256)
prep_kernel(const float* __restrict__ cb, const float* __restrict__ dither,
            float* __restrict__ dith, float* __restrict__ d2,
            short* __restrict__ Bp, unsigned* __restrict__ counts,
            unsigned* __restrict__ flagc) {
    __shared__ float S[64 * 65];
    const int t = threadIdx.x, b = blockIdx.x;
    const int gt = b * 256 + t;
    if (gt < 1024) counts[gt] = 0u;
    if (gt == 0) *flagc = 0u;
    const int kl = t >> 2, c = t & 3;
    const int k = b * 64 + kl;
    float dv[16];
    if (k < KM1) {
        float tt = dither[k];
        const float4* lo4 = (const float4*)(cb + (size_t)k * 64 + 16 * c);
        const float4* hi4 = (const float4*)(cb + (size_t)(k + 1) * 64 + 16 * c);
        #pragma unroll
        for (int q = 0; q < 4; ++q) {
            float4 lo = lo4[q], hi = hi4[q];
            dv[4 * q + 0] = lerp_exact(lo.x, hi.x, tt);
            dv[4 * q + 1] = lerp_exact(lo.y, hi.y, tt);
            dv[4 * q + 2] = lerp_exact(lo.z, hi.z, tt);
            dv[4 * q + 3] = lerp_exact(lo.w, hi.w, tt);
        }
    } else {
        #pragma unroll
        for (int q = 0; q < 16; ++q) dv[q] = 0.f;
    }
    // LDS copy for d2; plain dith for repair.
    {
        float* Sw = S + kl * 65 + 16 * c;
        float4* dd = (float4*)(dith + (size_t)k * 64 + 16 * c);
        #pragma unroll
        for (int q = 0; q < 4; ++q) {
            Sw[4 * q + 0] = dv[4 * q + 0]; Sw[4 * q + 1] = dv[4 * q + 1];
            Sw[4 * q + 2] = dv[4 * q + 2]; Sw[4 * q + 3] = dv[4 * q + 3];
            dd[q] = make_float4(dv[4 * q], dv[4 * q + 1], dv[4 * q + 2], dv[4 * q + 3]);
        }
    }
    // bf16 splits -> planes p = ((s*2+h)*4+g), plane = [1024 cols][8 bf16].
    {
        const int h = c >> 1;
        const int g0 = (c & 1) * 2;
        short s1[16], s2[16];
        #pragma unroll
        for (int j = 0; j < 16; ++j) {
            float v = dv[j];
            unsigned short u1 = f2bf(v);
            float r = v - bf2f(u1);
            s1[j] = (short)u1;
            s2[j] = (short)f2bf(r);
        }
        #pragma unroll
        for (int half = 0; half < 2; ++half) {   // j 0..7 -> g0, 8..15 -> g0+1
            const int g = g0 + half;
            bf16x8 v1, v2;
            #pragma unroll
            for (int j = 0; j < 8; ++j) { v1[j] = s1[half * 8 + j]; v2[j] = s2[half * 8 + j]; }
            *(bf16x8*)&Bp[(size_t)(((0 * 2 + h) * 4 + g)) * 8192 + k * 8] = v1;
            *(bf16x8*)&Bp[(size_t)(((1 * 2 + h) * 4 + g)) * 8192 + k * 8] = v2;
        }
    }
    __syncthreads();
    if (t < 64) {   // exact numpy 8-acc pairwise d2
        const float* Sr = S + t * 65;
        float r[8];
        #pragma unroll
        for (int j = 0; j < 8; ++j) {
            float x = Sr[j]; float bb = __fmul_rn(x, x); OPQ(bb); r[j] = bb;
        }
        #pragma unroll
        for (int i = 8; i < 64; i += 8) {
            #pragma unroll
            for (int j = 0; j < 8; ++j) {
                float x = Sr[i + j]; float bb = __fmul_rn(x, x); OPQ(bb);
                r[j] = __fadd_rn(r[j], bb);
            }
        }
        float s = __fadd_rn(
            __fadd_rn(__fadd_rn(r[0], r[1]), __fadd_rn(r[2], r[3])),
            __fadd_rn(__fadd_rn(r[4], r[5]), __fadd_rn(r[6], r[7])));
        int kk = b * 64 + t;
        d2[kk] = (kk >= KM1) ? 1e30f : s;
    }
}

// Kernel B: MFMA fast argmin + margin flagging.
// Block = 256 rows, 4 waves x 64 rows. A = split-bf16(2z) in VGPR frags.
// B planes staged per 128-col tile via global_load_lds (linear), dbuf.
// Per (rg, k16): C = sum of 6 MFMAs (a1b1,a2b1,a1b2 over 2 K-halves);
// score = d2[col] - C. Track best/second/idx; merge over 16 col-lanes.
__global__ void __launch_bounds__(256, 2)
mfma_argmin(const float* __restrict__ z_g,
            const short* __restrict__ Bp,
            const float* __restrict__ d2g,
            int* __restrict__ idx_out,
            unsigned* __restrict__ flagc,
            unsigned* __restrict__ flagl) {
    __shared__ short Bt[2][16384];   // [plane 16][128 cols][8 bf16], 32KB x2
    const int tid  = threadIdx.x;
    const int w    = tid >> 6;
    const int lane = tid & 63;
    const int colsel = lane & 15;
    const int g    = lane >> 4;
    const int rowbase = blockIdx.x << 8;
    const int wbase = rowbase + (w << 6);

    // Stage tile 0 (cols 0..127): 32 chunks of 1 KB; wave w -> chunks 8w..8w+7.
    #pragma unroll
    for (int j = 0; j < 8; ++j) {
        const int q = 8 * w + j;
        const int p = q >> 1, hh = q & 1;
        const short* gp = Bp + (size_t)p * 8192 + (hh * 64) * 8 + lane * 8;
        __builtin_amdgcn_global_load_lds((glob_void*)gp,
                                         (lds_void*)(&Bt[0][p * 1024 + hh * 512 + lane * 8]),
                                         16, 0, 0);
    }

    // A prologue: split-bf16 fragments of 2z for 4 row-groups x 2 K-halves.
    bf16x8 a1[4][2], a2[4][2];
    #pragma unroll
    for (int rg = 0; rg < 4; ++rg) {
        #pragma unroll
        for (int h = 0; h < 2; ++h) {
            const float* zp = z_g + ((size_t)(wbase + rg * 16 + colsel) << 6)
                              + h * 32 + (g << 3);
            float4 v0 = *(const float4*)zp;
            float4 v1 = *(const float4*)(zp + 4);
            float vv[8] = {v0.x, v0.y, v0.z, v0.w, v1.x, v1.y, v1.z, v1.w};
            bf16x8 x1, x2;
            #pragma unroll
            for (int j = 0; j < 8; ++j) {
                float tv = 2.f * vv[j];
                unsigned short u1 = f2bf(tv);
                float r = tv - bf2f(u1);
                x1[j] = (short)u1;
                x2[j] = (short)f2bf(r);
            }
            a1[rg][h] = x1; a2[rg][h] = x2;
        }
    }

    float best[16], second[16];
    int bidx[16];
    #pragma unroll
    for (int s16 = 0; s16 < 16; ++s16) {
        best[s16] = FLT_MAX; second[s16] = FLT_MAX; bidx[s16] = 0;
    }

    __syncthreads();   // tile 0 landed (barrier drains vmcnt)

    int buf = 0;
    #pragma unroll 1
    for (int t = 0; t < 8; ++t) {
        if (t < 7) {   // async-stage next tile into other buffer
            #pragma unroll
            for (int j = 0; j < 8; ++j) {
                const int q = 8 * w + j;
                const int p = q >> 1, hh = q & 1;
                const short* gp = Bp + (size_t)p * 8192
                                  + ((t + 1) * 128 + hh * 64) * 8 + lane * 8;
                __builtin_amdgcn_global_load_lds(
                    (glob_void*)gp,
                    (lds_void*)(&Bt[buf ^ 1][p * 1024 + hh * 512 + lane * 8]),
                    16, 0, 0);
            }
        }
        const short* Bb = &Bt[buf][0];
        #pragma unroll 1
        for (int q16 = 0; q16 < 8; ++q16) {
            const int loff = (q16 * 16 + colsel) * 8;
            bf16x8 b1h0 = *(const bf16x8*)&Bb[(0 + g) * 1024 + loff];
            bf16x8 b1h1 = *(const bf16x8*)&Bb[(4 + g) * 1024 + loff];
            bf16x8 b2h0 = *(const bf16x8*)&Bb[(8 + g) * 1024 + loff];
            bf16x8 b2h1 = *(const bf16x8*)&Bb[(12 + g) * 1024 + loff];
            const int col = t * 128 + q16 * 16 + colsel;
            const float e = d2g[col];
            #pragma unroll
            for (int rg = 0; rg < 4; ++rg) {
                f32x4 C = {0.f, 0.f, 0.f, 0.f};
                C = __builtin_amdgcn_mfma_f32_16x16x32_bf16(a1[rg][0], b1h0, C, 0, 0, 0);
                C = __builtin_amdgcn_mfma_f32_16x16x32_bf16(a1[rg][1], b1h1, C, 0, 0, 0);
                C = __builtin_amdgcn_mfma_f32_16x16x32_bf16(a2[rg][0], b1h0, C, 0, 0, 0);
                C = __builtin_amdgcn_mfma_f32_16x16x32_bf16(a2[rg][1], b1h1, C, 0, 0, 0);
                C = __builtin_amdgcn_mfma_f32_16x16x32_bf16(a1[rg][0], b2h0, C, 0, 0, 0);
                C = __builtin_amdgcn_mfma_f32_16x16x32_bf16(a1[rg][1], b2h1, C, 0, 0, 0);
                #pragma unroll
                for (int r = 0; r < 4; ++r) {
                    const int s16 = rg * 4 + r;
                    float sc = e - C[r];
                    if (sc < best[s16]) {
                        second[s16] = best[s16]; best[s16] = sc; bidx[s16] = col;
                    } else {
                        second[s16] = fminf(second[s16], sc);
                    }
                }
            }
        }
        __syncthreads();   // reads of Bt[buf] done; staged tile landed
        buf ^= 1;
    }

    // Merge across the 16 lanes sharing the same row set (xor within &15).
    #pragma unroll
    for (int d = 1; d <= 8; d <<= 1) {
        #pragma unroll
        for (int s16 = 0; s16 < 16; ++s16) {
            float bo = __shfl_xor(best[s16], d);
            float so = __shfl_xor(second[s16], d);
            int   io = __shfl_xor(bidx[s16], d);
            float ns = fminf(fminf(second[s16], so), fmaxf(best[s16], bo));
            if (bo < best[s16] || (bo == best[s16] && io < bidx[s16])) {
                best[s16] = bo; bidx[s16] = io;
            }
            second[s16] = ns;
        }
    }
    if (colsel == 0) {
        #pragma unroll
        for (int s16 = 0; s16 < 16; ++s16) {
            const int rg = s16 >> 2, r = s16 & 3;
            const int row = wbase + rg * 16 + g * 4 + r;
            idx_out[row] = bidx[s16];
            if (second[s16] - best[s16] < THR) {
                unsigned pos = atomicAdd(flagc, 1u);
                flagl[pos] = (unsigned)row;
            }
        }
    }
}

// Kernel C: exact numpy-replica repair for flagged rows. One wave per row;
// lane handles k in [lane*16, lane*16+16) ascending (first-index ties).
__global__ void __launch_bounds__(64)
repair_kernel(const float* __restrict__ z_g,
              const float* __restrict__ dith,
              const float* __restrict__ d2g,
              const unsigned* __restrict__ flagc,
              const unsigned* __restrict__ flagl,
              int* __restrict__ idx_out) {
    const int lane = threadIdx.x;
    const unsigned nf = *flagc;
    for (unsigned f = blockIdx.x; f < nf; f += gridDim.x) {
        const int row = (int)flagl[f];
        const float4* zr = (const float4*)(z_g + ((size_t)row << 6));
        float tz[64], zv[64];
        #pragma unroll
        for (int q = 0; q < 16; ++q) {
            float4 v = zr[q];
            zv[4 * q + 0] = v.x; zv[4 * q + 1] = v.y;
            zv[4 * q + 2] = v.z; zv[4 * q + 3] = v.w;
        }
        // zsum: numpy 8-acc pairwise over fl(z^2).
        float r8[8];
        #pragma unroll
        for (int j = 0; j < 8; ++j) {
            float x = zv[j]; float bb = __fmul_rn(x, x); OPQ(bb); r8[j] = bb;
        }
        #pragma unroll
        for (int i = 8; i < 64; i += 8) {
            #pragma unroll
            for (int j = 0; j < 8; ++j) {
                float x = zv[i + j]; float bb = __fmul_rn(x, x); OPQ(bb);
                r8[j] = __fadd_rn(r8[j], bb);
            }
        }
        const float zsum = __fadd_rn(
            __fadd_rn(__fadd_rn(r8[0], r8[1]), __fadd_rn(r8[2], r8[3])),
            __fadd_rn(__fadd_rn(r8[4], r8[5]), __fadd_rn(r8[6], r8[7])));
        #pragma unroll
        for (int i = 0; i < 64; ++i) tz[i] = __fadd_rn(zv[i], zv[i]);  // 2z exact

        float bv = FLT_MAX;
        int bk = 0;
        #pragma unroll 1
        for (int j = 0; j < 16; ++j) {
            const int k = lane * 16 + j;
            if (k >= KM1) break;
            const float* dk = dith + ((size_t)k << 6);
            float a = 0.f;
            #pragma unroll
            for (int i = 0; i < 64; ++i) a = fmaf(tz[i], dk[i], a);
            float D = __fsub_rn(__fadd_rn(zsum, d2g[k]), a);
            if (D < bv) { bv = D; bk = k; }
        }
        #pragma unroll
        for (int d = 1; d <= 32; d <<= 1) {
            float ov = __shfl_xor(bv, d);
            int   ok = __shfl_xor(bk, d);
            if (ov < bv || (ov == bv && ok < bk)) { bv = ov; bk = ok; }
        }
        if (lane == 0) idx_out[row] = bk;
    }
}

// Kernel D: per-row finalize. One wave per row (lane = dim).
__global__ void __launch_bounds__(256)
finalize_kernel(const float* __restrict__ z_g,
                const float* __restrict__ cb,
                const float* __restrict__ dither,
                const float* __restrict__ n1_g,
                const float* __restrict__ n2_g,
                const int* __restrict__ idx_arr,
                float* __restrict__ zq_out,
                float* __restrict__ idxf_out,
                unsigned* __restrict__ counts) {
    int wid = (blockIdx.x * 256 + threadIdx.x) >> 6;
    int lane = threadIdx.x & 63;
    int idx = idx_arr[wid];
    size_t base = (size_t)wid * DIM + lane;
    float z  = z_g[base];
    float n1 = n1_g[base];
    float n2 = n2_g[base];
    float c1 = cb[idx * DIM + lane];
    float c2 = cb[(idx + 1) * DIM + lane];
    float lam = dither[idx];
    float d1 = c1 - z, d2v = c2 - z;
    float r1 = n1 + d1, r2 = n2 + d2v;
    float s_r1 = r1 * r1, s_r2 = r2 * r2, s_d1 = d1 * d1, s_d2 = d2v * d2v;
    #pragma unroll
    for (int m = 32; m; m >>= 1) {
        s_r1 += __shfl_xor(s_r1, m, 64);
        s_r2 += __shfl_xor(s_r2, m, 64);
        s_d1 += __shfl_xor(s_d1, m, 64);
        s_d2 += __shfl_xor(s_d2, m, 64);
    }
    float em1 = sqrtf(s_d1), em2 = sqrtf(s_d2);
    float nr1 = fmaxf(sqrtf(s_r1), 1e-12f);
    float nr2 = fmaxf(sqrtf(s_r2), 1e-12f);
    float zq = z + em1 * (1.f - lam) * (r1 / nr1) + em2 * lam * (r2 / nr2);
    zq_out[base] = zq;
    if (lane == 0) {
        idxf_out[wid] = (float)idx;
        atomicAdd(&counts[idx], 1u);
    }
}

// Kernel E: perplexity from counts.
__global__ void ppl_kernel(const unsigned* __restrict__ counts,
                           float* __restrict__ out) {
    __shared__ float partial[16];
    int t = threadIdx.x;
    float p = (float)counts[t] * (1.f / (float)N_ROWS);
    float v = (p > 0.f) ? p * logf(p) : 0.f;
    #pragma unroll
    for (int m = 32; m; m >>= 1) v += __shfl_xor(v, m, 64);
    if ((t & 63) == 0) partial[t >> 6] = v;
    __syncthreads();
    if (t < 16) {
        float s = partial[t];
        #pragma unroll
        for (int m = 8; m; m >>= 1) s += __shfl_xor(s, m, 16);
        if (t == 0) out[0] = expf(-s);
    }
}

extern "C" void kernel_launch(void* const* d_in, const int* in_sizes, int n_in,
                              void* d_out, int out_size, void* d_ws, size_t ws_size,
                              hipStream_t stream) {
    const float* z      = (const float*)d_in[0];
    const float* cb     = (const float*)d_in[1];
    const float* dither = (const float*)d_in[2];
    const float* n1     = (const float*)d_in[3];
    const float* n2     = (const float*)d_in[4];

    char* ws = (char*)d_ws;
    float*    dith   = (float*)(ws + DITH_OFF);
    float*    d2     = (float*)(ws + D2_OFF);
    short*    Bp     = (short*)(ws + BP_OFF);
    unsigned* counts = (unsigned*)(ws + CNT_OFF);
    unsigned* flagc  = (unsigned*)(ws + FLAGC_OFF);
    unsigned* flagl  = (unsigned*)(ws + FLAGL_OFF);
    int*      idxa   = (int*)(ws + IDX_OFF);

    float* out  = (float*)d_out;
    float* zq   = out;
    float* idxf = out + (size_t)N_ROWS * DIM;
    float* ppl  = idxf + N_ROWS;

    prep_kernel<<<16, 256, 0, stream>>>(cb, dither, dith, d2, Bp, counts, flagc);
    mfma_argmin<<<N_ROWS / 256, 256, 0, stream>>>(z, Bp, d2, idxa, flagc, flagl);
    repair_kernel<<<2048, 64, 0, stream>>>(z, dith, d2, flagc, flagl, idxa);
    finalize_kernel<<<N_ROWS / 4, 256, 0, stream>>>(z, cb, dither, n1, n2,
                                                    idxa, zq, idxf, counts);
    ppl_kernel<<<1, 1024, 0, stream>>>(counts, ppl);
}

// Round 9
// 333.542 us; speedup vs baseline: 2.0437x; 2.0437x over previous
//
#include <hip/hip_runtime.h>
#include <math.h>
#include <float.h>

#define N_ROWS 131072
#define DIM 64
#define KM1 1023
#define THR 3e-5f

// ---- ws layout (bytes) ----
#define DT2_OFF   0         // float[64][1024] transposed, pre-doubled dith
#define D2_OFF    262144    // float[1024] exact-replica d2 (pad 1e30)
#define BP_OFF    266240    // bf16 planes: 16 x [1024 cols][8] = 256 KB
#define CNT_OFF   528384    // u32[1024]
#define FLAGC_OFF 532480    // u32 (+pad)
#define FLAGL_OFF 532544    // u32[131072]
#define IDX_OFF   1056832   // i32[131072]
// end ~1.58 MB

#define OPQ(x) asm volatile("" : "+v"(x))

typedef __attribute__((ext_vector_type(8))) short bf16x8;
typedef __attribute__((ext_vector_type(4))) float f32x4;
typedef __attribute__((address_space(3))) void lds_void;
typedef __attribute__((address_space(1))) const void glob_void;

__device__ __forceinline__ unsigned short f2bf(float x) {
    unsigned u = __float_as_uint(x);
    return (unsigned short)((u + 0x7fffu + ((u >> 16) & 1u)) >> 16);
}
__device__ __forceinline__ float bf2f(unsigned short b) {
    return __uint_as_float(((unsigned)b) << 16);
}

__device__ __forceinline__ float lerp_exact(float lo, float hi, float tt) {
    float hl = __fsub_rn(hi, lo);
    float p  = __fmul_rn(tt, hl);
    OPQ(p);
    float dv = __fadd_rn(lo, p);
    OPQ(dv);
    return dv;
}

// Kernel A: dithered codebook (exact numpy op order) -> transposed doubled
// dithT2 (repair), exact-replica d2, bf16-split B planes, zero counts/flagc.
__global__ void __launch_bounds__(256)
prep_kernel(const float* __restrict__ cb, const float* __restrict__ dither,
            float* __restrict__ dithT2, float* __restrict__ d2,
            short* __restrict__ Bp, unsigned* __restrict__ counts,
            unsigned* __restrict__ flagc) {
    __shared__ float S[64 * 65];
    const int t = threadIdx.x, b = blockIdx.x;
    const int gt = b * 256 + t;
    if (gt < 1024) counts[gt] = 0u;
    if (gt == 0) *flagc = 0u;
    const int kl = t >> 2, c = t & 3;
    const int k = b * 64 + kl;
    float dv[16];
    if (k < KM1) {
        float tt = dither[k];
        const float4* lo4 = (const float4*)(cb + (size_t)k * 64 + 16 * c);
        const float4* hi4 = (const float4*)(cb + (size_t)(k + 1) * 64 + 16 * c);
        #pragma unroll
        for (int q = 0; q < 4; ++q) {
            float4 lo = lo4[q], hi = hi4[q];
            dv[4 * q + 0] = lerp_exact(lo.x, hi.x, tt);
            dv[4 * q + 1] = lerp_exact(lo.y, hi.y, tt);
            dv[4 * q + 2] = lerp_exact(lo.z, hi.z, tt);
            dv[4 * q + 3] = lerp_exact(lo.w, hi.w, tt);
        }
    } else {
        #pragma unroll
        for (int q = 0; q < 16; ++q) dv[q] = 0.f;
    }
    {
        float* Sw = S + kl * 65 + 16 * c;
        #pragma unroll
        for (int q = 0; q < 16; ++q) Sw[q] = dv[q];
    }
    // bf16 splits -> planes p = ((s*2+h)*4+g), plane = [1024 cols][8 bf16].
    {
        const int h = c >> 1;
        const int g0 = (c & 1) * 2;
        short s1[16], s2[16];
        #pragma unroll
        for (int j = 0; j < 16; ++j) {
            float v = dv[j];
            unsigned short u1 = f2bf(v);
            float r = v - bf2f(u1);
            s1[j] = (short)u1;
            s2[j] = (short)f2bf(r);
        }
        #pragma unroll
        for (int half = 0; half < 2; ++half) {
            const int g = g0 + half;
            bf16x8 v1, v2;
            #pragma unroll
            for (int j = 0; j < 8; ++j) { v1[j] = s1[half * 8 + j]; v2[j] = s2[half * 8 + j]; }
            *(bf16x8*)&Bp[(size_t)(((0 * 2 + h) * 4 + g)) * 8192 + k * 8] = v1;
            *(bf16x8*)&Bp[(size_t)(((1 * 2 + h) * 4 + g)) * 8192 + k * 8] = v2;
        }
    }
    __syncthreads();
    if (t < 64) {   // exact numpy 8-acc pairwise d2
        const float* Sr = S + t * 65;
        float r[8];
        #pragma unroll
        for (int j = 0; j < 8; ++j) {
            float x = Sr[j]; float bb = __fmul_rn(x, x); OPQ(bb); r[j] = bb;
        }
        #pragma unroll
        for (int i = 8; i < 64; i += 8) {
            #pragma unroll
            for (int j = 0; j < 8; ++j) {
                float x = Sr[i + j]; float bb = __fmul_rn(x, x); OPQ(bb);
                r[j] = __fadd_rn(r[j], bb);
            }
        }
        float s = __fadd_rn(
            __fadd_rn(__fadd_rn(r[0], r[1]), __fadd_rn(r[2], r[3])),
            __fadd_rn(__fadd_rn(r[4], r[5]), __fadd_rn(r[6], r[7])));
        int kk = b * 64 + t;
        d2[kk] = (kk >= KM1) ? 1e30f : s;
    }
    // Transposed pre-doubled write: thread (i = t>>2, c) -> dithT2[i][b*64+16c..].
    {
        const int i = t >> 2;
        float v[16];
        #pragma unroll
        for (int j = 0; j < 16; ++j) {
            float x = S[(16 * c + j) * 65 + i];
            v[j] = __fadd_rn(x, x);            // exact 2x
        }
        float4* dst = (float4*)(dithT2 + (size_t)i * 1024 + b * 64 + 16 * c);
        dst[0] = make_float4(v[0], v[1], v[2], v[3]);
        dst[1] = make_float4(v[4], v[5], v[6], v[7]);
        dst[2] = make_float4(v[8], v[9], v[10], v[11]);
        dst[3] = make_float4(v[12], v[13], v[14], v[15]);
    }
}

// Kernel B: MFMA fast argmin + margin flagging (structure verified in R8).
// Block = 256 rows, 4 waves x 64 rows. A = split-bf16(2z) in VGPR frags.
// Per (rg, k16): C = 6 MFMAs; score = d2[col] - C; track best/second/idx.
__global__ void __launch_bounds__(256, 1)
mfma_argmin(const float* __restrict__ z_g,
            const short* __restrict__ Bp,
            const float* __restrict__ d2g,
            int* __restrict__ idx_out,
            unsigned* __restrict__ flagc,
            unsigned* __restrict__ flagl) {
    __shared__ short Bt[2][16384];   // [plane 16][128 cols][8 bf16], 32KB x2
    const int tid  = threadIdx.x;
    const int w    = tid >> 6;
    const int lane = tid & 63;
    const int colsel = lane & 15;
    const int g    = lane >> 4;
    const int rowbase = blockIdx.x << 8;
    const int wbase = rowbase + (w << 6);

    #pragma unroll
    for (int j = 0; j < 8; ++j) {
        const int q = 8 * w + j;
        const int p = q >> 1, hh = q & 1;
        const short* gp = Bp + (size_t)p * 8192 + (hh * 64) * 8 + lane * 8;
        __builtin_amdgcn_global_load_lds((glob_void*)gp,
                                         (lds_void*)(&Bt[0][p * 1024 + hh * 512 + lane * 8]),
                                         16, 0, 0);
    }

    bf16x8 a1[4][2], a2[4][2];
    #pragma unroll
    for (int rg = 0; rg < 4; ++rg) {
        #pragma unroll
        for (int h = 0; h < 2; ++h) {
            const float* zp = z_g + ((size_t)(wbase + rg * 16 + colsel) << 6)
                              + h * 32 + (g << 3);
            float4 v0 = *(const float4*)zp;
            float4 v1 = *(const float4*)(zp + 4);
            float vv[8] = {v0.x, v0.y, v0.z, v0.w, v1.x, v1.y, v1.z, v1.w};
            bf16x8 x1, x2;
            #pragma unroll
            for (int j = 0; j < 8; ++j) {
                float tv = 2.f * vv[j];
                unsigned short u1 = f2bf(tv);
                float r = tv - bf2f(u1);
                x1[j] = (short)u1;
                x2[j] = (short)f2bf(r);
            }
            a1[rg][h] = x1; a2[rg][h] = x2;
        }
    }

    float best[16], second[16];
    int bidx[16];
    #pragma unroll
    for (int s16 = 0; s16 < 16; ++s16) {
        best[s16] = FLT_MAX; second[s16] = FLT_MAX; bidx[s16] = 0;
    }

    __syncthreads();   // tile 0 landed

    int buf = 0;
    #pragma unroll 1
    for (int t = 0; t < 8; ++t) {
        if (t < 7) {
            #pragma unroll
            for (int j = 0; j < 8; ++j) {
                const int q = 8 * w + j;
                const int p = q >> 1, hh = q & 1;
                const short* gp = Bp + (size_t)p * 8192
                                  + ((t + 1) * 128 + hh * 64) * 8 + lane * 8;
                __builtin_amdgcn_global_load_lds(
                    (glob_void*)gp,
                    (lds_void*)(&Bt[buf ^ 1][p * 1024 + hh * 512 + lane * 8]),
                    16, 0, 0);
            }
        }
        const short* Bb = &Bt[buf][0];
        #pragma unroll 1
        for (int q16 = 0; q16 < 8; ++q16) {
            const int loff = (q16 * 16 + colsel) * 8;
            bf16x8 b1h0 = *(const bf16x8*)&Bb[(0 + g) * 1024 + loff];
            bf16x8 b1h1 = *(const bf16x8*)&Bb[(4 + g) * 1024 + loff];
            bf16x8 b2h0 = *(const bf16x8*)&Bb[(8 + g) * 1024 + loff];
            bf16x8 b2h1 = *(const bf16x8*)&Bb[(12 + g) * 1024 + loff];
            const int col = t * 128 + q16 * 16 + colsel;
            const float e = d2g[col];
            #pragma unroll
            for (int rg = 0; rg < 4; ++rg) {
                f32x4 C = {0.f, 0.f, 0.f, 0.f};
                C = __builtin_amdgcn_mfma_f32_16x16x32_bf16(a1[rg][0], b1h0, C, 0, 0, 0);
                C = __builtin_amdgcn_mfma_f32_16x16x32_bf16(a1[rg][1], b1h1, C, 0, 0, 0);
                C = __builtin_amdgcn_mfma_f32_16x16x32_bf16(a2[rg][0], b1h0, C, 0, 0, 0);
                C = __builtin_amdgcn_mfma_f32_16x16x32_bf16(a2[rg][1], b1h1, C, 0, 0, 0);
                C = __builtin_amdgcn_mfma_f32_16x16x32_bf16(a1[rg][0], b2h0, C, 0, 0, 0);
                C = __builtin_amdgcn_mfma_f32_16x16x32_bf16(a1[rg][1], b2h1, C, 0, 0, 0);
                #pragma unroll
                for (int r = 0; r < 4; ++r) {
                    const int s16 = rg * 4 + r;
                    float sc = e - C[r];
                    // branchless top-2 (provably identical to if/else form)
                    float up = fmaxf(best[s16], sc);
                    second[s16] = fminf(second[s16], up);
                    bool lt = sc < best[s16];
                    bidx[s16] = lt ? col : bidx[s16];
                    best[s16] = fminf(best[s16], sc);
                }
            }
        }
        __syncthreads();
        buf ^= 1;
    }

    #pragma unroll
    for (int d = 1; d <= 8; d <<= 1) {
        #pragma unroll
        for (int s16 = 0; s16 < 16; ++s16) {
            float bo = __shfl_xor(best[s16], d);
            float so = __shfl_xor(second[s16], d);
            int   io = __shfl_xor(bidx[s16], d);
            float ns = fminf(fminf(second[s16], so), fmaxf(best[s16], bo));
            if (bo < best[s16] || (bo == best[s16] && io < bidx[s16])) {
                best[s16] = bo; bidx[s16] = io;
            }
            second[s16] = ns;
        }
    }
    if (colsel == 0) {
        #pragma unroll
        for (int s16 = 0; s16 < 16; ++s16) {
            const int rg = s16 >> 2, r = s16 & 3;
            const int row = wbase + rg * 16 + g * 4 + r;
            idx_out[row] = bidx[s16];
            if (second[s16] - best[s16] < THR) {
                unsigned pos = atomicAdd(flagc, 1u);
                flagl[pos] = (unsigned)row;
            }
        }
    }
}

// Kernel C: exact numpy-replica repair. One wave per flagged row; lane owns
// k = c4*256 + lane*4 + j (16 parallel chains); dithT2 reads coalesced;
// z broadcast via shfl. Chains bit-identical to the BLAS-replica.
__global__ void __launch_bounds__(256)
repair_kernel(const float* __restrict__ z_g,
              const float* __restrict__ dithT2,
              const float* __restrict__ d2g,
              const unsigned* __restrict__ flagc,
              const unsigned* __restrict__ flagl,
              int* __restrict__ idx_out) {
    const int w = threadIdx.x >> 6;
    const int lane = threadIdx.x & 63;
    const unsigned nf = *flagc;
    for (unsigned f = blockIdx.x * 4 + w; f < nf; f += gridDim.x * 4) {
        const int row = (int)flagl[f];
        const float zl = z_g[((size_t)row << 6) + lane];
        // zsum: numpy 8-acc pairwise over fl(z^2), identical bits in all lanes.
        float zq = __fmul_rn(zl, zl); OPQ(zq);
        float r8[8];
        #pragma unroll
        for (int j = 0; j < 8; ++j) r8[j] = __shfl(zq, j);
        #pragma unroll
        for (int m = 1; m < 8; ++m) {
            #pragma unroll
            for (int j = 0; j < 8; ++j)
                r8[j] = __fadd_rn(r8[j], __shfl(zq, 8 * m + j));
        }
        const float zsum = __fadd_rn(
            __fadd_rn(__fadd_rn(r8[0], r8[1]), __fadd_rn(r8[2], r8[3])),
            __fadd_rn(__fadd_rn(r8[4], r8[5]), __fadd_rn(r8[6], r8[7])));

        float acc[4][4];
        #pragma unroll
        for (int c4 = 0; c4 < 4; ++c4)
            #pragma unroll
            for (int j = 0; j < 4; ++j) acc[c4][j] = 0.f;

        const float* base = dithT2 + lane * 4;
        #pragma unroll 8
        for (int i = 0; i < 64; ++i) {
            const float zi = __shfl(zl, i);
            const float4 dA = *(const float4*)(base + i * 1024 + 0);
            const float4 dB = *(const float4*)(base + i * 1024 + 256);
            const float4 dC = *(const float4*)(base + i * 1024 + 512);
            const float4 dD = *(const float4*)(base + i * 1024 + 768);
            acc[0][0] = fmaf(zi, dA.x, acc[0][0]);
            acc[0][1] = fmaf(zi, dA.y, acc[0][1]);
            acc[0][2] = fmaf(zi, dA.z, acc[0][2]);
            acc[0][3] = fmaf(zi, dA.w, acc[0][3]);
            acc[1][0] = fmaf(zi, dB.x, acc[1][0]);
            acc[1][1] = fmaf(zi, dB.y, acc[1][1]);
            acc[1][2] = fmaf(zi, dB.z, acc[1][2]);
            acc[1][3] = fmaf(zi, dB.w, acc[1][3]);
            acc[2][0] = fmaf(zi, dC.x, acc[2][0]);
            acc[2][1] = fmaf(zi, dC.y, acc[2][1]);
            acc[2][2] = fmaf(zi, dC.z, acc[2][2]);
            acc[2][3] = fmaf(zi, dC.w, acc[2][3]);
            acc[3][0] = fmaf(zi, dD.x, acc[3][0]);
            acc[3][1] = fmaf(zi, dD.y, acc[3][1]);
            acc[3][2] = fmaf(zi, dD.z, acc[3][2]);
            acc[3][3] = fmaf(zi, dD.w, acc[3][3]);
        }
        float bv = FLT_MAX;
        int bk = 0;
        #pragma unroll
        for (int c4 = 0; c4 < 4; ++c4) {
            const float4 e = *(const float4*)(d2g + c4 * 256 + lane * 4);
            const float ee[4] = {e.x, e.y, e.z, e.w};
            #pragma unroll
            for (int j = 0; j < 4; ++j) {
                const int k = c4 * 256 + lane * 4 + j;
                float D = __fsub_rn(__fadd_rn(zsum, ee[j]), acc[c4][j]);
                if (D < bv) { bv = D; bk = k; }   // ascending k per lane
            }
        }
        #pragma unroll
        for (int d = 1; d <= 32; d <<= 1) {
            float ov = __shfl_xor(bv, d);
            int   ok = __shfl_xor(bk, d);
            if (ov < bv || (ov == bv && ok < bk)) { bv = ov; bk = ok; }
        }
        if (lane == 0) idx_out[row] = bk;
    }
}

// Kernel D: per-row finalize. One wave per row (lane = dim).
__global__ void __launch_bounds__(256)
finalize_kernel(const float* __restrict__ z_g,
                const float* __restrict__ cb,
                const float* __restrict__ dither,
                const float* __restrict__ n1_g,
                const float* __restrict__ n2_g,
                const int* __restrict__ idx_arr,
                float* __restrict__ zq_out,
                float* __restrict__ idxf_out,
                unsigned* __restrict__ counts) {
    int wid = (blockIdx.x * 256 + threadIdx.x) >> 6;
    int lane = threadIdx.x & 63;
    int idx = idx_arr[wid];
    size_t base = (size_t)wid * DIM + lane;
    float z  = z_g[base];
    float n1 = n1_g[base];
    float n2 = n2_g[base];
    float c1 = cb[idx * DIM + lane];
    float c2 = cb[(idx + 1) * DIM + lane];
    float lam = dither[idx];
    float d1 = c1 - z, d2v = c2 - z;
    float r1 = n1 + d1, r2 = n2 + d2v;
    float s_r1 = r1 * r1, s_r2 = r2 * r2, s_d1 = d1 * d1, s_d2 = d2v * d2v;
    #pragma unroll
    for (int m = 32; m; m >>= 1) {
        s_r1 += __shfl_xor(s_r1, m, 64);
        s_r2 += __shfl_xor(s_r2, m, 64);
        s_d1 += __shfl_xor(s_d1, m, 64);
        s_d2 += __shfl_xor(s_d2, m, 64);
    }
    float em1 = sqrtf(s_d1), em2 = sqrtf(s_d2);
    float nr1 = fmaxf(sqrtf(s_r1), 1e-12f);
    float nr2 = fmaxf(sqrtf(s_r2), 1e-12f);
    float zq = z + em1 * (1.f - lam) * (r1 / nr1) + em2 * lam * (r2 / nr2);
    zq_out[base] = zq;
    if (lane == 0) {
        idxf_out[wid] = (float)idx;
        atomicAdd(&counts[idx], 1u);
    }
}

// Kernel E: perplexity from counts.
__global__ void ppl_kernel(const unsigned* __restrict__ counts,
                           float* __restrict__ out) {
    __shared__ float partial[16];
    int t = threadIdx.x;
    float p = (float)counts[t] * (1.f / (float)N_ROWS);
    float v = (p > 0.f) ? p * logf(p) : 0.f;
    #pragma unroll
    for (int m = 32; m; m >>= 1) v += __shfl_xor(v, m, 64);
    if ((t & 63) == 0) partial[t >> 6] = v;
    __syncthreads();
    if (t < 16) {
        float s = partial[t];
        #pragma unroll
        for (int m = 8; m; m >>= 1) s += __shfl_xor(s, m, 16);
        if (t == 0) out[0] = expf(-s);
    }
}

extern "C" void kernel_launch(void* const* d_in, const int* in_sizes, int n_in,
                              void* d_out, int out_size, void* d_ws, size_t ws_size,
                              hipStream_t stream) {
    const float* z      = (const float*)d_in[0];
    const float* cb     = (const float*)d_in[1];
    const float* dither = (const float*)d_in[2];
    const float* n1     = (const float*)d_in[3];
    const float* n2     = (const float*)d_in[4];

    char* ws = (char*)d_ws;
    float*    dithT2 = (float*)(ws + DT2_OFF);
    float*    d2     = (float*)(ws + D2_OFF);
    short*    Bp     = (short*)(ws + BP_OFF);
    unsigned* counts = (unsigned*)(ws + CNT_OFF);
    unsigned* flagc  = (unsigned*)(ws + FLAGC_OFF);
    unsigned* flagl  = (unsigned*)(ws + FLAGL_OFF);
    int*      idxa   = (int*)(ws + IDX_OFF);

    float* out  = (float*)d_out;
    float* zq   = out;
    float* idxf = out + (size_t)N_ROWS * DIM;
    float* ppl  = idxf + N_ROWS;

    prep_kernel<<<16, 256, 0, stream>>>(cb, dither, dithT2, d2, Bp, counts, flagc);
    mfma_argmin<<<N_ROWS / 256, 256, 0, stream>>>(z, Bp, d2, idxa, flagc, flagl);
    repair_kernel<<<1024, 256, 0, stream>>>(z, dithT2, d2, flagc, flagl, idxa);
    finalize_kernel<<<N_ROWS / 4, 256, 0, stream>>>(z, cb, dither, n1, n2,
                                                    idxa, zq, idxf, counts);
    ppl_kernel<<<1, 1024, 0, stream>>>(counts, ppl);
}